// Round 4
// baseline (146.225 us; speedup 1.0000x reference)
//
#include <hip/hip_runtime.h>
#include <hip/hip_bf16.h>

#define BB 4
#define NN 4096
#define DD 256
#define MM (BB * NN)      // 16384 rows
#define MAXNZ 128
#define WCAP 96
// grid: 256 groups x 67 blocks = 3 GEMM + 64 deg per group
#define NGRP 256
#define GPER 67
#define TOTAL_BLKS (NGRP * GPER)   // 17152

using bf16x8 = __attribute__((ext_vector_type(8))) __bf16;
using f32x4  = __attribute__((ext_vector_type(4))) float;

__device__ __forceinline__ unsigned short f2bf(float f) {
    union { float f; unsigned u; } x; x.f = f;
    unsigned r = x.u + 0x7fffu + ((x.u >> 16) & 1u);
    return (unsigned short)(r >> 16);
}
__device__ __forceinline__ float bf2f(unsigned short s) {
    union { unsigned u; float f; } x; x.u = ((unsigned)s) << 16;
    return x.f;
}

__device__ __forceinline__ void gload16(const void* g, void* l) {
    __builtin_amdgcn_global_load_lds(
        (const __attribute__((address_space(1))) unsigned int*)g,
        (__attribute__((address_space(3))) unsigned int*)l,
        16, 0, 0);   // 16B/lane: lds dest = base + lane*16 (wave-uniform base)
}

// ---------------- kernel 0: one-time bf16 conversion ----------------
// blocks [0,4096): x fp32 -> xb bf16 (linear). blocks [4096,4288): weights
// fp32 [k][n] -> wb bf16 [s][n][k] (transposed so GEMM B-tiles stage linearly).
__global__ __launch_bounds__(256) void k_cvt(const float* __restrict__ x,
                                             const float* __restrict__ theta,
                                             const float* __restrict__ Wh,
                                             const float* __restrict__ Wt,
                                             unsigned short* __restrict__ xb,
                                             unsigned short* __restrict__ wb) {
    const int bx = blockIdx.x;
    const int tid = threadIdx.x;
    if (bx < 4096) {
        size_t e4 = (size_t)bx * 256 + tid;          // float4 index, 1M total
        float4 v = *(const float4*)(x + e4 * 4);
        ushort4 o;
        o.x = f2bf(v.x); o.y = f2bf(v.y); o.z = f2bf(v.z); o.w = f2bf(v.w);
        *(ushort4*)(xb + e4 * 4) = o;
    } else {
        int wt = (bx - 4096) * 256 + tid;            // 0..49151
        int s   = wt >> 14;                          // 0..2
        int rem = wt & 16383;
        int k   = rem >> 6;                          // 0..255
        int n4  = (rem & 63) << 2;                   // 0..252
        const float* W = (s == 0) ? theta : ((s == 1) ? Wh : Wt);
        float4 v = *(const float4*)(W + k * DD + n4);
        unsigned short* dst = wb + ((size_t)s << 16);
        dst[(size_t)(n4 + 0) * DD + k] = f2bf(v.x);
        dst[(size_t)(n4 + 1) * DD + k] = f2bf(v.y);
        dst[(size_t)(n4 + 2) * DD + k] = f2bf(v.z);
        dst[(size_t)(n4 + 3) * DD + k] = f2bf(v.w);
    }
}

// ------------- fused kernel: deg scan (BW-bound) + triple GEMM (MFMA) -------------
// GEMM: 128x128 tile, BK=64, global_load_lds(16B) staging, T2 XOR-swizzle
// (linear LDS dest + inverse-swizzled global source + swizzled ds_read).
__global__ __launch_bounds__(256) void k_prep(const unsigned short* __restrict__ xb,
                                              const unsigned short* __restrict__ wb,
                                              const float* __restrict__ bt,
                                              const float* __restrict__ adj,
                                              float* __restrict__ norm,
                                              int* __restrict__ cnt,
                                              unsigned short* __restrict__ idx,
                                              unsigned short* __restrict__ h,
                                              unsigned short* __restrict__ het,
                                              unsigned short* __restrict__ gate) {
    __shared__ __align__(16) unsigned short AB[2 * 128 * 64];  // A: [0,8192), B: [8192,16384) ushorts
    __shared__ unsigned short part[4][WCAP];
    __shared__ int wcnt[4];

    const int bx  = blockIdx.x;
    const int q   = bx / GPER;
    const int r   = bx % GPER;
    const int tid = threadIdx.x;
    const int wave = tid >> 6;
    const int lane = tid & 63;

    if (r < 3) {
        // ---------------- GEMM role ----------------
        const int g   = q * 3 + r;              // 0..767
        const int m0  = (g & 127) * 128;        // row block
        const int nt  = g >> 7;                 // 0..5
        const int seg = nt >> 1;                // 0:theta 1:Wh 2:Wt
        const int ns0 = (nt & 1) * 128;         // col within 256-col segment

        const int lm = lane & 15;
        const int kg = lane >> 4;               // 0..3
        const int wm = (wave >> 1) * 64;
        const int wn = (wave & 1) * 64;

        const int rsub = lane >> 3;                    // 0..7 (row within 8-row stage chunk)
        const int ksw  = 8 * ((lane & 7) ^ rsub);      // inverse-swizzled k elem offset

        f32x4 acc[4][4] = {};

        for (int kt = 0; kt < 4; ++kt) {
            const int k0 = kt * 64;
            // stage A: 16 x 1KB chunks (8 rows each); this wave does 4
#pragma unroll
            for (int it = 0; it < 4; ++it) {
                int t = wave * 4 + it;
                const unsigned short* ga = xb + (size_t)(m0 + t * 8 + rsub) * DD + k0 + ksw;
                gload16(ga, &AB[t * 512]);
            }
            // stage B from wb[seg][n][k]
#pragma unroll
            for (int it = 0; it < 4; ++it) {
                int t = wave * 4 + it;
                const unsigned short* gb = wb + ((size_t)seg << 16)
                                         + (size_t)(ns0 + t * 8 + rsub) * DD + k0 + ksw;
                gload16(gb, &AB[8192 + t * 512]);
            }
            __syncthreads();
#pragma unroll
            for (int ks = 0; ks < 2; ++ks) {
                const int cb = ks * 64 + kg * 16;      // col byte within 128B row
                bf16x8 a[4], b[4];
#pragma unroll
                for (int i = 0; i < 4; ++i) {
                    int rw = wm + i * 16 + lm;
                    a[i] = *(const bf16x8*)((const char*)AB + rw * 128 + (cb ^ ((rw & 7) << 4)));
                }
#pragma unroll
                for (int j = 0; j < 4; ++j) {
                    int rw = wn + j * 16 + lm;
                    b[j] = *(const bf16x8*)((const char*)AB + 16384 + rw * 128 + (cb ^ ((rw & 7) << 4)));
                }
#pragma unroll
                for (int i = 0; i < 4; ++i)
#pragma unroll
                    for (int j = 0; j < 4; ++j)
                        acc[i][j] = __builtin_amdgcn_mfma_f32_16x16x32_bf16(a[i], b[j], acc[i][j], 0, 0, 0);
            }
            __syncthreads();
        }

        const int rbase = (lane >> 4) * 4;
#pragma unroll
        for (int i = 0; i < 4; ++i) {
#pragma unroll
            for (int j = 0; j < 4; ++j) {
                int cseg = ns0 + wn + j * 16 + lm;     // 0..255 within segment
#pragma unroll
                for (int rr = 0; rr < 4; ++rr) {
                    int grow = m0 + wm + i * 16 + rbase + rr;
                    float v = acc[i][j][rr];
                    size_t off = (size_t)grow * DD + cseg;
                    if (seg == 0) {
                        h[off] = f2bf(v);                       // unscaled; norms applied in spmm
                    } else if (seg == 1) {
                        het[off] = f2bf(v);
                    } else {
                        float gt = 1.f / (1.f + expf(-(v + bt[cseg])));
                        gate[off] = f2bf(gt);
                    }
                }
            }
        }
    } else {
        // ---------------- deg role (deterministic ballot compaction) ----------------
        const int row = q * 64 + (r - 3);       // 0..16383
        const float4* arow4 = (const float4*)(adj + (size_t)row * NN);
        const unsigned long long lmask = (1ull << lane) - 1ull;
        unsigned int cw = 0;
        const int cbase = wave * 1024;
#pragma unroll
        for (int s = 0; s < 4; ++s) {
            float4 v = arow4[wave * 256 + s * 64 + lane];
            int col = cbase + s * 256 + lane * 4;
            unsigned long long m;
            int p;
            m = __ballot(v.x != 0.f);
            if (v.x != 0.f) { p = cw + __popcll(m & lmask); if (p < WCAP) part[wave][p] = (unsigned short)(col + 0); }
            cw += (unsigned)__popcll(m);
            m = __ballot(v.y != 0.f);
            if (v.y != 0.f) { p = cw + __popcll(m & lmask); if (p < WCAP) part[wave][p] = (unsigned short)(col + 1); }
            cw += (unsigned)__popcll(m);
            m = __ballot(v.z != 0.f);
            if (v.z != 0.f) { p = cw + __popcll(m & lmask); if (p < WCAP) part[wave][p] = (unsigned short)(col + 2); }
            cw += (unsigned)__popcll(m);
            m = __ballot(v.w != 0.f);
            if (v.w != 0.f) { p = cw + __popcll(m & lmask); if (p < WCAP) part[wave][p] = (unsigned short)(col + 3); }
            cw += (unsigned)__popcll(m);
        }
        if (lane == 0) wcnt[wave] = (int)cw;
        __syncthreads();
        const int w0 = wcnt[0], w1 = wcnt[1], w2 = wcnt[2], w3 = wcnt[3];
        const int total = w0 + w1 + w2 + w3;
        const int l0 = w0 < WCAP ? w0 : WCAP;
        const int l1 = w1 < WCAP ? w1 : WCAP;
        const int l2 = w2 < WCAP ? w2 : WCAP;
        const int l3 = w3 < WCAP ? w3 : WCAP;
        const int base1 = l0, base2 = l0 + l1, base3 = l0 + l1 + l2;
        int c = base3 + l3;
        if (c > MAXNZ) c = MAXNZ;
        for (int t = tid; t < c; t += 256) {
            int sg, of;
            if (t >= base3)      { sg = 3; of = t - base3; }
            else if (t >= base2) { sg = 2; of = t - base2; }
            else if (t >= base1) { sg = 1; of = t - base1; }
            else                 { sg = 0; of = t; }
            idx[(size_t)row * MAXNZ + t] = part[sg][of];
        }
        if (tid == 0) {
            cnt[row] = c;
            norm[row] = rsqrtf((float)total + 1e-6f);
        }
    }
}

// ---------------- kernel 2: gather-SpMM + blend + ELU (wave per row) ----------------
__global__ __launch_bounds__(256) void k_spmm(const unsigned short* __restrict__ h,
                                              const unsigned short* __restrict__ het,
                                              const unsigned short* __restrict__ gate,
                                              const float* __restrict__ norm,
                                              const int* __restrict__ cnt,
                                              const unsigned short* __restrict__ idx,
                                              float* __restrict__ out) {
    __shared__ unsigned short sj[4][MAXNZ];
    __shared__ float sn[4][MAXNZ];
    const int wave = threadIdx.x >> 6;
    const int lane = threadIdx.x & 63;
    const int row  = blockIdx.x * 4 + wave;
    const int b    = row >> 12;
    int c = cnt[row];
    if (c > MAXNZ) c = MAXNZ;
    const unsigned short* ip = idx + (size_t)row * MAXNZ;
    const float* nb = norm + (b << 12);
    for (int t = lane; t < c; t += 64) {
        unsigned short j = ip[t];
        sj[wave][t] = j;
        sn[wave][t] = nb[j];
    }
    __syncthreads();

    const unsigned short* hp = h + ((size_t)(b << 12)) * DD + lane * 4;
    f32x4 acc = {0.f, 0.f, 0.f, 0.f};
    int t = 0;
    for (; t + 4 <= c; t += 4) {
        int j0 = sj[wave][t + 0]; float w0 = sn[wave][t + 0];
        int j1 = sj[wave][t + 1]; float w1 = sn[wave][t + 1];
        int j2 = sj[wave][t + 2]; float w2 = sn[wave][t + 2];
        int j3 = sj[wave][t + 3]; float w3 = sn[wave][t + 3];
        ushort4 v0 = *(const ushort4*)(hp + (size_t)j0 * DD);
        ushort4 v1 = *(const ushort4*)(hp + (size_t)j1 * DD);
        ushort4 v2 = *(const ushort4*)(hp + (size_t)j2 * DD);
        ushort4 v3 = *(const ushort4*)(hp + (size_t)j3 * DD);
        acc.x += w0 * bf2f(v0.x) + w1 * bf2f(v1.x) + w2 * bf2f(v2.x) + w3 * bf2f(v3.x);
        acc.y += w0 * bf2f(v0.y) + w1 * bf2f(v1.y) + w2 * bf2f(v2.y) + w3 * bf2f(v3.y);
        acc.z += w0 * bf2f(v0.z) + w1 * bf2f(v1.z) + w2 * bf2f(v2.z) + w3 * bf2f(v3.z);
        acc.w += w0 * bf2f(v0.w) + w1 * bf2f(v1.w) + w2 * bf2f(v2.w) + w3 * bf2f(v3.w);
    }
    for (; t < c; ++t) {
        int j = sj[wave][t]; float wv = sn[wave][t];
        ushort4 v = *(const ushort4*)(hp + (size_t)j * DD);
        acc.x += wv * bf2f(v.x);
        acc.y += wv * bf2f(v.y);
        acc.z += wv * bf2f(v.z);
        acc.w += wv * bf2f(v.w);
    }

    const float nrm = norm[row];
    const size_t off = (size_t)row * DD + lane * 4;
    ushort4 hv = *(const ushort4*)(het + off);
    ushort4 gv = *(const ushort4*)(gate + off);
    float4 o;
    {
        float fhom, fh, g, val;
        fhom = acc.x * nrm; fh = bf2f(hv.x); g = bf2f(gv.x);
        val = g * fhom + (1.f - g) * fh; o.x = (val > 0.f) ? val : (expf(val) - 1.f);
        fhom = acc.y * nrm; fh = bf2f(hv.y); g = bf2f(gv.y);
        val = g * fhom + (1.f - g) * fh; o.y = (val > 0.f) ? val : (expf(val) - 1.f);
        fhom = acc.z * nrm; fh = bf2f(hv.z); g = bf2f(gv.z);
        val = g * fhom + (1.f - g) * fh; o.z = (val > 0.f) ? val : (expf(val) - 1.f);
        fhom = acc.w * nrm; fh = bf2f(hv.w); g = bf2f(gv.w);
        val = g * fhom + (1.f - g) * fh; o.w = (val > 0.f) ? val : (expf(val) - 1.f);
    }
    *(float4*)(out + off) = o;
}

extern "C" void kernel_launch(void* const* d_in, const int* in_sizes, int n_in,
                              void* d_out, int out_size, void* d_ws, size_t ws_size,
                              hipStream_t stream) {
    const float* x     = (const float*)d_in[0];
    const float* adj   = (const float*)d_in[1];
    const float* theta = (const float*)d_in[2];
    const float* Wh    = (const float*)d_in[3];
    const float* Wt    = (const float*)d_in[4];
    const float* bt    = (const float*)d_in[5];
    float* out = (float*)d_out;

    char* w = (char*)d_ws;
    float* norm          = (float*)w;                                   // 64 KB
    int*   cnt           = (int*)(w + (size_t)MM * 4);                  // 64 KB
    unsigned short* idx  = (unsigned short*)(w + (size_t)MM * 8);       // 4 MB
    unsigned short* h    = (unsigned short*)(w + (size_t)MM * 8 + (size_t)MM * MAXNZ * 2);
    unsigned short* het  = h + (size_t)MM * DD;                         // 8 MB each
    unsigned short* gate = het + (size_t)MM * DD;
    unsigned short* xb   = gate + (size_t)MM * DD;                      // 8 MB
    unsigned short* wb   = xb + (size_t)MM * DD;                        // 384 KB

    k_cvt<<<dim3(4288), dim3(256), 0, stream>>>(x, theta, Wh, Wt, xb, wb);
    k_prep<<<dim3(TOTAL_BLKS), dim3(256), 0, stream>>>(xb, wb, bt, adj,
                                                       norm, cnt, idx, h, het, gate);
    k_spmm<<<dim3(MM / 4), dim3(256), 0, stream>>>(h, het, gate, norm, cnt, idx, out);
}

// Round 5
// 100.420 us; speedup vs baseline: 1.4561x; 1.4561x over previous
//
#include <hip/hip_runtime.h>
#include <hip/hip_bf16.h>

#define BB 4
#define NN 4096
#define DD 256
#define MM (BB * NN)      // 16384 rows
#define MAXNZ 128
#define WCAP 96
// grid: 1024 groups x 19 blocks = 3 GEMM + 16 deg per group (R3 ratio)
#define GPER 19
#define TOTAL_BLKS (1024 * GPER)   // 19456

using bf16x8 = __attribute__((ext_vector_type(8))) __bf16;
using f32x4  = __attribute__((ext_vector_type(4))) float;

__device__ __forceinline__ unsigned short f2bf(float f) {
    union { float f; unsigned u; } x; x.f = f;
    unsigned r = x.u + 0x7fffu + ((x.u >> 16) & 1u);
    return (unsigned short)(r >> 16);
}
__device__ __forceinline__ float bf2f(unsigned short s) {
    union { unsigned u; float f; } x; x.u = ((unsigned)s) << 16;
    return x.f;
}

__device__ __forceinline__ void gload16(const void* g, void* l) {
    __builtin_amdgcn_global_load_lds(
        (const __attribute__((address_space(1))) unsigned int*)g,
        (__attribute__((address_space(3))) unsigned int*)l,
        16, 0, 0);   // 16B/lane: lds dest = base + lane*16 (wave-uniform base)
}

// ---------------- kernel 0: one-time bf16 conversion ----------------
__global__ __launch_bounds__(256) void k_cvt(const float* __restrict__ x,
                                             const float* __restrict__ theta,
                                             const float* __restrict__ Wh,
                                             const float* __restrict__ Wt,
                                             unsigned short* __restrict__ xb,
                                             unsigned short* __restrict__ wb) {
    const int bx = blockIdx.x;
    const int tid = threadIdx.x;
    if (bx < 4096) {
        size_t e4 = (size_t)bx * 256 + tid;          // float4 index, 1M total
        float4 v = *(const float4*)(x + e4 * 4);
        ushort4 o;
        o.x = f2bf(v.x); o.y = f2bf(v.y); o.z = f2bf(v.z); o.w = f2bf(v.w);
        *(ushort4*)(xb + e4 * 4) = o;
    } else {
        int wt = (bx - 4096) * 256 + tid;            // 0..49151
        int s   = wt >> 14;                          // 0..2
        int rem = wt & 16383;
        int k   = rem >> 6;                          // 0..255
        int n4  = (rem & 63) << 2;                   // 0..252
        const float* W = (s == 0) ? theta : ((s == 1) ? Wh : Wt);
        float4 v = *(const float4*)(W + k * DD + n4);
        unsigned short* dst = wb + ((size_t)s << 16);
        dst[(size_t)(n4 + 0) * DD + k] = f2bf(v.x);
        dst[(size_t)(n4 + 1) * DD + k] = f2bf(v.y);
        dst[(size_t)(n4 + 2) * DD + k] = f2bf(v.z);
        dst[(size_t)(n4 + 3) * DD + k] = f2bf(v.w);
    }
}

// ------------- fused kernel: deg scan (BW-bound) + triple GEMM (MFMA) -------------
// 64x64 GEMM tiles, global_load_lds(16B) staging with both-sides XOR swizzle,
// 16.8 KB LDS -> 9 blocks/CU so the co-resident deg stream keeps HBM saturated.
__global__ __launch_bounds__(256) void k_prep(const unsigned short* __restrict__ xb,
                                              const unsigned short* __restrict__ wb,
                                              const float* __restrict__ bt,
                                              const float* __restrict__ adj,
                                              float* __restrict__ norm,
                                              int* __restrict__ cnt,
                                              unsigned short* __restrict__ idx,
                                              unsigned short* __restrict__ h,
                                              unsigned short* __restrict__ het,
                                              unsigned short* __restrict__ gate) {
    __shared__ __align__(16) unsigned short AB[8192];     // A: [0,4096) shorts, B: [4096,8192)
    __shared__ unsigned short part[4][WCAP];
    __shared__ int wcnt[4];

    const int bx  = blockIdx.x;
    const int q   = bx / GPER;
    const int r   = bx % GPER;
    const int tid = threadIdx.x;
    const int wave = tid >> 6;
    const int lane = tid & 63;

    if (r < 3) {
        // ---------------- GEMM role ----------------
        const int g   = q * 3 + r;              // 0..3071
        const int m0  = (g & 255) * 64;         // row block
        const int yb  = g >> 8;                 // 0..11
        const int seg = yb >> 2;                // 0:theta 1:Wh 2:Wt
        const int n0  = (yb & 3) * 64;          // col within 256-col segment

        const int lm = lane & 15;
        const int kg = lane >> 4;               // 0..3
        const int wm = (wave >> 1) * 32;
        const int wn = (wave & 1) * 32;

        const int rsub = lane >> 3;                    // 0..7 (row within 8-row chunk)
        const int ksw  = 8 * ((lane & 7) ^ rsub);      // inverse-swizzled k elem offset

        const unsigned short* wseg = wb + ((size_t)seg << 16);

        f32x4 acc[2][2] = {};

        for (int kt = 0; kt < 4; ++kt) {
            const int k0 = kt * 64;
            // stage A (64x64 bf16 = 8KB, 8 chunks of 8 rows) + B; 2+2 chunks/wave
#pragma unroll
            for (int it = 0; it < 2; ++it) {
                int t = wave * 2 + it;
                const unsigned short* ga = xb + (size_t)(m0 + t * 8 + rsub) * DD + k0 + ksw;
                gload16(ga, &AB[t * 512]);
                const unsigned short* gb = wseg + (size_t)(n0 + t * 8 + rsub) * DD + k0 + ksw;
                gload16(gb, &AB[4096 + t * 512]);
            }
            __syncthreads();
#pragma unroll
            for (int ks = 0; ks < 2; ++ks) {
                const int cb = ks * 64 + kg * 16;      // col byte within 128B row
                bf16x8 a[2], b[2];
#pragma unroll
                for (int i = 0; i < 2; ++i) {
                    int rw = wm + i * 16 + lm;
                    a[i] = *(const bf16x8*)((const char*)AB + rw * 128 + (cb ^ ((rw & 7) << 4)));
                }
#pragma unroll
                for (int j = 0; j < 2; ++j) {
                    int rw = wn + j * 16 + lm;
                    b[j] = *(const bf16x8*)((const char*)AB + 8192 + rw * 128 + (cb ^ ((rw & 7) << 4)));
                }
#pragma unroll
                for (int i = 0; i < 2; ++i)
#pragma unroll
                    for (int j = 0; j < 2; ++j)
                        acc[i][j] = __builtin_amdgcn_mfma_f32_16x16x32_bf16(a[i], b[j], acc[i][j], 0, 0, 0);
            }
            __syncthreads();
        }

        const int rbase = (lane >> 4) * 4;
#pragma unroll
        for (int i = 0; i < 2; ++i) {
#pragma unroll
            for (int j = 0; j < 2; ++j) {
                int cseg = n0 + wn + j * 16 + lm;      // 0..255 within segment
#pragma unroll
                for (int rr = 0; rr < 4; ++rr) {
                    int grow = m0 + wm + i * 16 + rbase + rr;
                    float v = acc[i][j][rr];
                    size_t off = (size_t)grow * DD + cseg;
                    if (seg == 0) {
                        h[off] = f2bf(v);                       // unscaled; norms applied in spmm
                    } else if (seg == 1) {
                        het[off] = f2bf(v);
                    } else {
                        float gt = 1.f / (1.f + expf(-(v + bt[cseg])));
                        gate[off] = f2bf(gt);
                    }
                }
            }
        }
    } else {
        // ---------------- deg role (deterministic ballot compaction) ----------------
        const int row = q * 16 + (r - 3);       // 0..16383
        const float4* arow4 = (const float4*)(adj + (size_t)row * NN);
        const unsigned long long lmask = (1ull << lane) - 1ull;
        unsigned int cw = 0;
        const int cbase = wave * 1024;
#pragma unroll
        for (int s = 0; s < 4; ++s) {
            float4 v = arow4[wave * 256 + s * 64 + lane];
            int col = cbase + s * 256 + lane * 4;
            unsigned long long m;
            int p;
            m = __ballot(v.x != 0.f);
            if (v.x != 0.f) { p = cw + __popcll(m & lmask); if (p < WCAP) part[wave][p] = (unsigned short)(col + 0); }
            cw += (unsigned)__popcll(m);
            m = __ballot(v.y != 0.f);
            if (v.y != 0.f) { p = cw + __popcll(m & lmask); if (p < WCAP) part[wave][p] = (unsigned short)(col + 1); }
            cw += (unsigned)__popcll(m);
            m = __ballot(v.z != 0.f);
            if (v.z != 0.f) { p = cw + __popcll(m & lmask); if (p < WCAP) part[wave][p] = (unsigned short)(col + 2); }
            cw += (unsigned)__popcll(m);
            m = __ballot(v.w != 0.f);
            if (v.w != 0.f) { p = cw + __popcll(m & lmask); if (p < WCAP) part[wave][p] = (unsigned short)(col + 3); }
            cw += (unsigned)__popcll(m);
        }
        if (lane == 0) wcnt[wave] = (int)cw;
        __syncthreads();
        const int w0 = wcnt[0], w1 = wcnt[1], w2 = wcnt[2], w3 = wcnt[3];
        const int total = w0 + w1 + w2 + w3;
        const int l0 = w0 < WCAP ? w0 : WCAP;
        const int l1 = w1 < WCAP ? w1 : WCAP;
        const int l2 = w2 < WCAP ? w2 : WCAP;
        const int l3 = w3 < WCAP ? w3 : WCAP;
        const int base1 = l0, base2 = l0 + l1, base3 = l0 + l1 + l2;
        int c = base3 + l3;
        if (c > MAXNZ) c = MAXNZ;
        for (int t = tid; t < c; t += 256) {
            int sg, of;
            if (t >= base3)      { sg = 3; of = t - base3; }
            else if (t >= base2) { sg = 2; of = t - base2; }
            else if (t >= base1) { sg = 1; of = t - base1; }
            else                 { sg = 0; of = t; }
            idx[(size_t)row * MAXNZ + t] = part[sg][of];
        }
        if (tid == 0) {
            cnt[row] = c;
            norm[row] = rsqrtf((float)total + 1e-6f);
        }
    }
}

// ---------------- kernel 2: gather-SpMM + blend + ELU (wave per row) ----------------
__global__ __launch_bounds__(256) void k_spmm(const unsigned short* __restrict__ h,
                                              const unsigned short* __restrict__ het,
                                              const unsigned short* __restrict__ gate,
                                              const float* __restrict__ norm,
                                              const int* __restrict__ cnt,
                                              const unsigned short* __restrict__ idx,
                                              float* __restrict__ out) {
    __shared__ unsigned short sj[4][MAXNZ];
    __shared__ float sn[4][MAXNZ];
    const int wave = threadIdx.x >> 6;
    const int lane = threadIdx.x & 63;
    const int row  = blockIdx.x * 4 + wave;
    const int b    = row >> 12;
    int c = cnt[row];
    if (c > MAXNZ) c = MAXNZ;
    const unsigned short* ip = idx + (size_t)row * MAXNZ;
    const float* nb = norm + (b << 12);
    for (int t = lane; t < c; t += 64) {
        unsigned short j = ip[t];
        sj[wave][t] = j;
        sn[wave][t] = nb[j];
    }
    __syncthreads();

    const unsigned short* hp = h + ((size_t)(b << 12)) * DD + lane * 4;
    f32x4 acc = {0.f, 0.f, 0.f, 0.f};
    int t = 0;
    for (; t + 4 <= c; t += 4) {
        int j0 = sj[wave][t + 0]; float w0 = sn[wave][t + 0];
        int j1 = sj[wave][t + 1]; float w1 = sn[wave][t + 1];
        int j2 = sj[wave][t + 2]; float w2 = sn[wave][t + 2];
        int j3 = sj[wave][t + 3]; float w3 = sn[wave][t + 3];
        ushort4 v0 = *(const ushort4*)(hp + (size_t)j0 * DD);
        ushort4 v1 = *(const ushort4*)(hp + (size_t)j1 * DD);
        ushort4 v2 = *(const ushort4*)(hp + (size_t)j2 * DD);
        ushort4 v3 = *(const ushort4*)(hp + (size_t)j3 * DD);
        acc.x += w0 * bf2f(v0.x) + w1 * bf2f(v1.x) + w2 * bf2f(v2.x) + w3 * bf2f(v3.x);
        acc.y += w0 * bf2f(v0.y) + w1 * bf2f(v1.y) + w2 * bf2f(v2.y) + w3 * bf2f(v3.y);
        acc.z += w0 * bf2f(v0.z) + w1 * bf2f(v1.z) + w2 * bf2f(v2.z) + w3 * bf2f(v3.z);
        acc.w += w0 * bf2f(v0.w) + w1 * bf2f(v1.w) + w2 * bf2f(v2.w) + w3 * bf2f(v3.w);
    }
    for (; t < c; ++t) {
        int j = sj[wave][t]; float wv = sn[wave][t];
        ushort4 v = *(const ushort4*)(hp + (size_t)j * DD);
        acc.x += wv * bf2f(v.x);
        acc.y += wv * bf2f(v.y);
        acc.z += wv * bf2f(v.z);
        acc.w += wv * bf2f(v.w);
    }

    const float nrm = norm[row];
    const size_t off = (size_t)row * DD + lane * 4;
    ushort4 hv = *(const ushort4*)(het + off);
    ushort4 gv = *(const ushort4*)(gate + off);
    float4 o;
    {
        float fhom, fh, g, val;
        fhom = acc.x * nrm; fh = bf2f(hv.x); g = bf2f(gv.x);
        val = g * fhom + (1.f - g) * fh; o.x = (val > 0.f) ? val : (expf(val) - 1.f);
        fhom = acc.y * nrm; fh = bf2f(hv.y); g = bf2f(gv.y);
        val = g * fhom + (1.f - g) * fh; o.y = (val > 0.f) ? val : (expf(val) - 1.f);
        fhom = acc.z * nrm; fh = bf2f(hv.z); g = bf2f(gv.z);
        val = g * fhom + (1.f - g) * fh; o.z = (val > 0.f) ? val : (expf(val) - 1.f);
        fhom = acc.w * nrm; fh = bf2f(hv.w); g = bf2f(gv.w);
        val = g * fhom + (1.f - g) * fh; o.w = (val > 0.f) ? val : (expf(val) - 1.f);
    }
    *(float4*)(out + off) = o;
}

extern "C" void kernel_launch(void* const* d_in, const int* in_sizes, int n_in,
                              void* d_out, int out_size, void* d_ws, size_t ws_size,
                              hipStream_t stream) {
    const float* x     = (const float*)d_in[0];
    const float* adj   = (const float*)d_in[1];
    const float* theta = (const float*)d_in[2];
    const float* Wh    = (const float*)d_in[3];
    const float* Wt    = (const float*)d_in[4];
    const float* bt    = (const float*)d_in[5];
    float* out = (float*)d_out;

    char* w = (char*)d_ws;
    float* norm          = (float*)w;                                   // 64 KB
    int*   cnt           = (int*)(w + (size_t)MM * 4);                  // 64 KB
    unsigned short* idx  = (unsigned short*)(w + (size_t)MM * 8);       // 4 MB
    unsigned short* h    = (unsigned short*)(w + (size_t)MM * 8 + (size_t)MM * MAXNZ * 2);
    unsigned short* het  = h + (size_t)MM * DD;                         // 8 MB each
    unsigned short* gate = het + (size_t)MM * DD;
    unsigned short* xb   = gate + (size_t)MM * DD;                      // 8 MB
    unsigned short* wb   = xb + (size_t)MM * DD;                        // 384 KB

    k_cvt<<<dim3(4288), dim3(256), 0, stream>>>(x, theta, Wh, Wt, xb, wb);
    k_prep<<<dim3(TOTAL_BLKS), dim3(256), 0, stream>>>(xb, wb, bt, adj,
                                                       norm, cnt, idx, h, het, gate);
    k_spmm<<<dim3(MM / 4), dim3(256), 0, stream>>>(h, het, gate, norm, cnt, idx, out);
}

// Round 6
// 99.370 us; speedup vs baseline: 1.4715x; 1.0106x over previous
//
#include <hip/hip_runtime.h>
#include <hip/hip_bf16.h>

#define BB 4
#define NN 4096
#define DD 256
#define MM (BB * NN)      // 16384 rows
#define MAXNZ 128
#define WCAP 96
// grid: 1024 groups x 19 blocks = 3 GEMM + 16 deg per group
#define GPER 19
#define TOTAL_BLKS (1024 * GPER)   // 19456

using bf16x8 = __attribute__((ext_vector_type(8))) __bf16;
using f32x4  = __attribute__((ext_vector_type(4))) float;
using f32x4e = __attribute__((ext_vector_type(4))) float;
using u16x4e = __attribute__((ext_vector_type(4))) unsigned short;

__device__ __forceinline__ unsigned short f2bf(float f) {
    union { float f; unsigned u; } x; x.f = f;
    unsigned r = x.u + 0x7fffu + ((x.u >> 16) & 1u);
    return (unsigned short)(r >> 16);
}
__device__ __forceinline__ float bf2f(unsigned short s) {
    union { unsigned u; float f; } x; x.u = ((unsigned)s) << 16;
    return x.f;
}

__device__ __forceinline__ void gload16(const void* g, void* l) {
    __builtin_amdgcn_global_load_lds(
        (const __attribute__((address_space(1))) unsigned int*)g,
        (__attribute__((address_space(3))) unsigned int*)l,
        16, 0, 0);   // 16B/lane: lds dest = base + lane*16 (wave-uniform base)
}

// ---------------- kernel 0: one-time bf16 conversion ----------------
__global__ __launch_bounds__(256) void k_cvt(const float* __restrict__ x,
                                             const float* __restrict__ theta,
                                             const float* __restrict__ Wh,
                                             const float* __restrict__ Wt,
                                             unsigned short* __restrict__ xb,
                                             unsigned short* __restrict__ wb) {
    const int bx = blockIdx.x;
    const int tid = threadIdx.x;
    if (bx < 4096) {
        size_t e4 = (size_t)bx * 256 + tid;          // float4 index, 1M total
        f32x4e v = __builtin_nontemporal_load((const f32x4e*)x + e4);   // x read once
        ushort4 o;
        o.x = f2bf(v[0]); o.y = f2bf(v[1]); o.z = f2bf(v[2]); o.w = f2bf(v[3]);
        *(ushort4*)(xb + e4 * 4) = o;                // cached: re-read 12x by prep
    } else {
        int wt = (bx - 4096) * 256 + tid;            // 0..49151
        int s   = wt >> 14;                          // 0..2
        int rem = wt & 16383;
        int k   = rem >> 6;                          // 0..255
        int n4  = (rem & 63) << 2;                   // 0..252
        const float* W = (s == 0) ? theta : ((s == 1) ? Wh : Wt);
        f32x4e v = __builtin_nontemporal_load((const f32x4e*)(W + k * DD + n4));
        unsigned short* dst = wb + ((size_t)s << 16);
        dst[(size_t)(n4 + 0) * DD + k] = f2bf(v[0]);
        dst[(size_t)(n4 + 1) * DD + k] = f2bf(v[1]);
        dst[(size_t)(n4 + 2) * DD + k] = f2bf(v[2]);
        dst[(size_t)(n4 + 3) * DD + k] = f2bf(v[3]);
    }
}

// ------------- fused kernel: deg scan (BW-bound) + triple GEMM (MFMA) -------------
// adj is a 268MB zero-reuse stream: nontemporal loads keep it from evicting
// xb/wb (GEMM staging reuse) out of L2/L3.
__global__ __launch_bounds__(256) void k_prep(const unsigned short* __restrict__ xb,
                                              const unsigned short* __restrict__ wb,
                                              const float* __restrict__ bt,
                                              const float* __restrict__ adj,
                                              float* __restrict__ norm,
                                              int* __restrict__ cnt,
                                              unsigned short* __restrict__ idx,
                                              unsigned short* __restrict__ h,
                                              unsigned short* __restrict__ het,
                                              unsigned short* __restrict__ gate) {
    __shared__ __align__(16) unsigned short AB[8192];     // A: [0,4096) shorts, B: [4096,8192)
    __shared__ unsigned short part[4][WCAP];
    __shared__ int wcnt[4];

    const int bx  = blockIdx.x;
    const int q   = bx / GPER;
    const int r   = bx % GPER;
    const int tid = threadIdx.x;
    const int wave = tid >> 6;
    const int lane = tid & 63;

    if (r < 3) {
        // ---------------- GEMM role ----------------
        const int g   = q * 3 + r;              // 0..3071
        const int m0  = (g & 255) * 64;         // row block
        const int yb  = g >> 8;                 // 0..11
        const int seg = yb >> 2;                // 0:theta 1:Wh 2:Wt
        const int n0  = (yb & 3) * 64;          // col within 256-col segment

        const int lm = lane & 15;
        const int kg = lane >> 4;               // 0..3
        const int wm = (wave >> 1) * 32;
        const int wn = (wave & 1) * 32;

        const int rsub = lane >> 3;                    // 0..7 (row within 8-row chunk)
        const int ksw  = 8 * ((lane & 7) ^ rsub);      // inverse-swizzled k elem offset

        const unsigned short* wseg = wb + ((size_t)seg << 16);

        f32x4 acc[2][2] = {};

        for (int kt = 0; kt < 4; ++kt) {
            const int k0 = kt * 64;
#pragma unroll
            for (int it = 0; it < 2; ++it) {
                int t = wave * 2 + it;
                const unsigned short* ga = xb + (size_t)(m0 + t * 8 + rsub) * DD + k0 + ksw;
                gload16(ga, &AB[t * 512]);
                const unsigned short* gb = wseg + (size_t)(n0 + t * 8 + rsub) * DD + k0 + ksw;
                gload16(gb, &AB[4096 + t * 512]);
            }
            __syncthreads();
#pragma unroll
            for (int ks = 0; ks < 2; ++ks) {
                const int cb = ks * 64 + kg * 16;      // col byte within 128B row
                bf16x8 a[2], b[2];
#pragma unroll
                for (int i = 0; i < 2; ++i) {
                    int rw = wm + i * 16 + lm;
                    a[i] = *(const bf16x8*)((const char*)AB + rw * 128 + (cb ^ ((rw & 7) << 4)));
                }
#pragma unroll
                for (int j = 0; j < 2; ++j) {
                    int rw = wn + j * 16 + lm;
                    b[j] = *(const bf16x8*)((const char*)AB + 8192 + rw * 128 + (cb ^ ((rw & 7) << 4)));
                }
#pragma unroll
                for (int i = 0; i < 2; ++i)
#pragma unroll
                    for (int j = 0; j < 2; ++j)
                        acc[i][j] = __builtin_amdgcn_mfma_f32_16x16x32_bf16(a[i], b[j], acc[i][j], 0, 0, 0);
            }
            __syncthreads();
        }

        const int rbase = (lane >> 4) * 4;
#pragma unroll
        for (int i = 0; i < 2; ++i) {
#pragma unroll
            for (int j = 0; j < 2; ++j) {
                int cseg = n0 + wn + j * 16 + lm;      // 0..255 within segment
#pragma unroll
                for (int rr = 0; rr < 4; ++rr) {
                    int grow = m0 + wm + i * 16 + rbase + rr;
                    float v = acc[i][j][rr];
                    size_t off = (size_t)grow * DD + cseg;
                    if (seg == 0) {
                        h[off] = f2bf(v);                       // cached: gathered by spmm
                    } else if (seg == 1) {
                        het[off] = f2bf(v);
                    } else {
                        float gt = 1.f / (1.f + expf(-(v + bt[cseg])));
                        gate[off] = f2bf(gt);
                    }
                }
            }
        }
    } else {
        // ---------------- deg role (deterministic ballot compaction) ----------------
        const int row = q * 16 + (r - 3);       // 0..16383
        const f32x4e* arow4 = (const f32x4e*)(adj + (size_t)row * NN);
        const unsigned long long lmask = (1ull << lane) - 1ull;
        unsigned int cw = 0;
        const int cbase = wave * 1024;
#pragma unroll
        for (int s = 0; s < 4; ++s) {
            f32x4e v = __builtin_nontemporal_load(arow4 + wave * 256 + s * 64 + lane);
            int col = cbase + s * 256 + lane * 4;
            unsigned long long m;
            int p;
            m = __ballot(v[0] != 0.f);
            if (v[0] != 0.f) { p = cw + __popcll(m & lmask); if (p < WCAP) part[wave][p] = (unsigned short)(col + 0); }
            cw += (unsigned)__popcll(m);
            m = __ballot(v[1] != 0.f);
            if (v[1] != 0.f) { p = cw + __popcll(m & lmask); if (p < WCAP) part[wave][p] = (unsigned short)(col + 1); }
            cw += (unsigned)__popcll(m);
            m = __ballot(v[2] != 0.f);
            if (v[2] != 0.f) { p = cw + __popcll(m & lmask); if (p < WCAP) part[wave][p] = (unsigned short)(col + 2); }
            cw += (unsigned)__popcll(m);
            m = __ballot(v[3] != 0.f);
            if (v[3] != 0.f) { p = cw + __popcll(m & lmask); if (p < WCAP) part[wave][p] = (unsigned short)(col + 3); }
            cw += (unsigned)__popcll(m);
        }
        if (lane == 0) wcnt[wave] = (int)cw;
        __syncthreads();
        const int w0 = wcnt[0], w1 = wcnt[1], w2 = wcnt[2], w3 = wcnt[3];
        const int total = w0 + w1 + w2 + w3;
        const int l0 = w0 < WCAP ? w0 : WCAP;
        const int l1 = w1 < WCAP ? w1 : WCAP;
        const int l2 = w2 < WCAP ? w2 : WCAP;
        const int l3 = w3 < WCAP ? w3 : WCAP;
        const int base1 = l0, base2 = l0 + l1, base3 = l0 + l1 + l2;
        int c = base3 + l3;
        if (c > MAXNZ) c = MAXNZ;
        for (int t = tid; t < c; t += 256) {
            int sg, of;
            if (t >= base3)      { sg = 3; of = t - base3; }
            else if (t >= base2) { sg = 2; of = t - base2; }
            else if (t >= base1) { sg = 1; of = t - base1; }
            else                 { sg = 0; of = t; }
            idx[(size_t)row * MAXNZ + t] = part[sg][of];
        }
        if (tid == 0) {
            cnt[row] = c;
            norm[row] = rsqrtf((float)total + 1e-6f);
        }
    }
}

// ---------------- kernel 2: gather-SpMM + blend + ELU (wave per row) ----------------
// h gathers stay on the cached path (L2-resident); het/gate/idx are read-once
// and out is write-once -> nontemporal, preserving L2 for h.
__global__ __launch_bounds__(256) void k_spmm(const unsigned short* __restrict__ h,
                                              const unsigned short* __restrict__ het,
                                              const unsigned short* __restrict__ gate,
                                              const float* __restrict__ norm,
                                              const int* __restrict__ cnt,
                                              const unsigned short* __restrict__ idx,
                                              float* __restrict__ out) {
    __shared__ unsigned short sj[4][MAXNZ];
    __shared__ float sn[4][MAXNZ];
    const int wave = threadIdx.x >> 6;
    const int lane = threadIdx.x & 63;
    const int row  = blockIdx.x * 4 + wave;
    const int b    = row >> 12;
    int c = cnt[row];
    if (c > MAXNZ) c = MAXNZ;
    const unsigned short* ip = idx + (size_t)row * MAXNZ;
    const float* nb = norm + (b << 12);
    for (int t = lane; t < c; t += 64) {
        unsigned short j = __builtin_nontemporal_load(ip + t);
        sj[wave][t] = j;
        sn[wave][t] = nb[j];
    }
    __syncthreads();

    const unsigned short* hp = h + ((size_t)(b << 12)) * DD + lane * 4;
    f32x4 acc = {0.f, 0.f, 0.f, 0.f};
    int t = 0;
    for (; t + 4 <= c; t += 4) {
        int j0 = sj[wave][t + 0]; float w0 = sn[wave][t + 0];
        int j1 = sj[wave][t + 1]; float w1 = sn[wave][t + 1];
        int j2 = sj[wave][t + 2]; float w2 = sn[wave][t + 2];
        int j3 = sj[wave][t + 3]; float w3 = sn[wave][t + 3];
        ushort4 v0 = *(const ushort4*)(hp + (size_t)j0 * DD);
        ushort4 v1 = *(const ushort4*)(hp + (size_t)j1 * DD);
        ushort4 v2 = *(const ushort4*)(hp + (size_t)j2 * DD);
        ushort4 v3 = *(const ushort4*)(hp + (size_t)j3 * DD);
        acc.x += w0 * bf2f(v0.x) + w1 * bf2f(v1.x) + w2 * bf2f(v2.x) + w3 * bf2f(v3.x);
        acc.y += w0 * bf2f(v0.y) + w1 * bf2f(v1.y) + w2 * bf2f(v2.y) + w3 * bf2f(v3.y);
        acc.z += w0 * bf2f(v0.z) + w1 * bf2f(v1.z) + w2 * bf2f(v2.z) + w3 * bf2f(v3.z);
        acc.w += w0 * bf2f(v0.w) + w1 * bf2f(v1.w) + w2 * bf2f(v2.w) + w3 * bf2f(v3.w);
    }
    for (; t < c; ++t) {
        int j = sj[wave][t]; float wv = sn[wave][t];
        ushort4 v = *(const ushort4*)(hp + (size_t)j * DD);
        acc.x += wv * bf2f(v.x);
        acc.y += wv * bf2f(v.y);
        acc.z += wv * bf2f(v.z);
        acc.w += wv * bf2f(v.w);
    }

    const float nrm = norm[row];
    const size_t off = (size_t)row * DD + lane * 4;
    u16x4e hv = __builtin_nontemporal_load((const u16x4e*)(het + off));
    u16x4e gv = __builtin_nontemporal_load((const u16x4e*)(gate + off));
    f32x4e o;
    {
        float fhom, fh, g, val;
        fhom = acc.x * nrm; fh = bf2f(hv[0]); g = bf2f(gv[0]);
        val = g * fhom + (1.f - g) * fh; o[0] = (val > 0.f) ? val : (expf(val) - 1.f);
        fhom = acc.y * nrm; fh = bf2f(hv[1]); g = bf2f(gv[1]);
        val = g * fhom + (1.f - g) * fh; o[1] = (val > 0.f) ? val : (expf(val) - 1.f);
        fhom = acc.z * nrm; fh = bf2f(hv[2]); g = bf2f(gv[2]);
        val = g * fhom + (1.f - g) * fh; o[2] = (val > 0.f) ? val : (expf(val) - 1.f);
        fhom = acc.w * nrm; fh = bf2f(hv[3]); g = bf2f(gv[3]);
        val = g * fhom + (1.f - g) * fh; o[3] = (val > 0.f) ? val : (expf(val) - 1.f);
    }
    __builtin_nontemporal_store(o, (f32x4e*)(out + off));
}

extern "C" void kernel_launch(void* const* d_in, const int* in_sizes, int n_in,
                              void* d_out, int out_size, void* d_ws, size_t ws_size,
                              hipStream_t stream) {
    const float* x     = (const float*)d_in[0];
    const float* adj   = (const float*)d_in[1];
    const float* theta = (const float*)d_in[2];
    const float* Wh    = (const float*)d_in[3];
    const float* Wt    = (const float*)d_in[4];
    const float* bt    = (const float*)d_in[5];
    float* out = (float*)d_out;

    char* w = (char*)d_ws;
    float* norm          = (float*)w;                                   // 64 KB
    int*   cnt           = (int*)(w + (size_t)MM * 4);                  // 64 KB
    unsigned short* idx  = (unsigned short*)(w + (size_t)MM * 8);       // 4 MB
    unsigned short* h    = (unsigned short*)(w + (size_t)MM * 8 + (size_t)MM * MAXNZ * 2);
    unsigned short* het  = h + (size_t)MM * DD;                         // 8 MB each
    unsigned short* gate = het + (size_t)MM * DD;
    unsigned short* xb   = gate + (size_t)MM * DD;                      // 8 MB
    unsigned short* wb   = xb + (size_t)MM * DD;                        // 384 KB

    k_cvt<<<dim3(4288), dim3(256), 0, stream>>>(x, theta, Wh, Wt, xb, wb);
    k_prep<<<dim3(TOTAL_BLKS), dim3(256), 0, stream>>>(xb, wb, bt, adj,
                                                       norm, cnt, idx, h, het, gate);
    k_spmm<<<dim3(MM / 4), dim3(256), 0, stream>>>(h, het, gate, norm, cnt, idx, out);
}